// Round 1
// baseline (202.746 us; speedup 1.0000x reference)
//
#include <hip/hip_runtime.h>
#include <math.h>

#define ALPHA_ 0.2f
#define N_ 16
#define H_ 32
#define W_ 32
#define T_ 16
#define V_ 64
#define P_ (H_*W_)  // 1024

// ---------------------------------------------------------------------------
// Kernel 1: conv. grid = N*H (512), block = 256 (64 v-lanes x 4 w-groups).
// Wh stored as (b, t, p, v), p = h*32+w.
// ---------------------------------------------------------------------------
__global__ __launch_bounds__(256) void conv_k(const float* __restrict__ X,
                                              const float* __restrict__ CW,
                                              const float* __restrict__ CB,
                                              float* __restrict__ Wh) {
    __shared__ float s_cw[2304];  // [(dh*3+dw)][ti][t]
    __shared__ float s_cb[16];
    int tid = threadIdx.x;
    for (int i = tid; i < 2304; i += 256) s_cw[i] = CW[i];
    if (tid < 16) s_cb[tid] = CB[tid];
    __syncthreads();

    int b  = blockIdx.x >> 5;
    int hh = blockIdx.x & 31;
    int v  = tid & 63;
    int wg = tid >> 6;  // 0..3

    const float* Xb = X + (size_t)b * (H_*W_*T_*V_) + v;

    for (int wc = 0; wc < 2; ++wc) {
        int w0 = wg * 8 + wc * 4;
        float acc[4][16];
        #pragma unroll
        for (int u = 0; u < 4; ++u)
            #pragma unroll
            for (int t = 0; t < 16; ++t) acc[u][t] = s_cb[t];

        for (int dh = 0; dh < 3; ++dh) {
            int hy = hh + dh - 1;
            if ((unsigned)hy >= (unsigned)H_) continue;
            for (int dw = 0; dw < 3; ++dw) {
                const float* wrow = &s_cw[(dh*3 + dw) * 256];
                #pragma unroll
                for (int ti = 0; ti < 16; ++ti) {
                    float xv[4];
                    #pragma unroll
                    for (int u = 0; u < 4; ++u) {
                        int wx = w0 + u + dw - 1;
                        xv[u] = ((unsigned)wx < (unsigned)W_)
                              ? Xb[(((size_t)hy*W_ + wx)*T_ + ti) * V_] : 0.f;
                    }
                    #pragma unroll
                    for (int t = 0; t < 16; ++t) {
                        float wt = wrow[ti*16 + t];
                        #pragma unroll
                        for (int u = 0; u < 4; ++u) acc[u][t] += xv[u] * wt;
                    }
                }
            }
        }
        #pragma unroll
        for (int t = 0; t < 16; ++t) {
            #pragma unroll
            for (int u = 0; u < 4; ++u) {
                int p = hh*W_ + w0 + u;
                Wh[(((size_t)b*T_ + t)*P_ + p)*V_ + v] = acc[u][t];
            }
        }
    }
}

// ---------------------------------------------------------------------------
// Kernel 2: Ei/Ej. grid = N*T (256) blocks of 256.
// Ei[b,v,q] = sum_{e,w,t} Wh[b,t,(2q+e)*32+w,v] * a[e*1024+w*16+t]
// Ej same with +512 offset into a. Stored (b, v, q) contiguous in q.
// ---------------------------------------------------------------------------
__global__ __launch_bounds__(256) void eiej_k(const float* __restrict__ Wh,
                                              const float* __restrict__ av,
                                              float* __restrict__ Ei,
                                              float* __restrict__ Ej) {
    int b = blockIdx.x >> 4;
    int q = blockIdx.x & 15;
    int tid = threadIdx.x, v = tid & 63, g = tid >> 6;  // g: 4 t-groups

    float si = 0.f, sj = 0.f;
    for (int e = 0; e < 2; ++e) {
        int hh = 2*q + e;
        #pragma unroll
        for (int tt = 0; tt < 4; ++tt) {
            int t = g*4 + tt;
            const float* base = Wh + (((size_t)b*T_ + t)*P_ + hh*W_) * V_ + v;
            #pragma unroll 8
            for (int w = 0; w < 32; ++w) {
                float x  = base[(size_t)w * V_];
                float ai = av[e*1024 + w*16 + t];
                float aj = av[e*1024 + w*16 + t + 512];
                si += x * ai;
                sj += x * aj;
            }
        }
    }
    __shared__ float ri[4][64], rj[4][64];
    ri[g][v] = si; rj[g][v] = sj;
    __syncthreads();
    if (g == 0) {
        float a0 = ri[0][v] + ri[1][v] + ri[2][v] + ri[3][v];
        float a1 = rj[0][v] + rj[1][v] + rj[2][v] + rj[3][v];
        Ei[((size_t)b*V_ + v)*T_ + q] = a0;
        Ej[((size_t)b*V_ + v)*T_ + q] = a1;
    }
}

// ---------------------------------------------------------------------------
// Kernel 3a: adj_norm from B. 1 block, 64 threads (one wave), lane = row.
// ---------------------------------------------------------------------------
__global__ __launch_bounds__(64) void adjn_k(const float* __restrict__ Bm,
                                             float* __restrict__ adjn) {
    int i = threadIdx.x;  // row 0..63
    float row[64];
    float mn = 1e30f, mx = -1e30f;
    #pragma unroll
    for (int v = 0; v < 64; ++v) {
        float x = Bm[i*64 + v] + (v == i ? 1.f : 0.f);
        row[v] = x;
        mn = fminf(mn, x);
        mx = fmaxf(mx, x);
    }
    #pragma unroll
    for (int off = 32; off > 0; off >>= 1) {
        mn = fminf(mn, __shfl_xor(mn, off));
        mx = fmaxf(mx, __shfl_xor(mx, off));
    }
    float inv = 1.f / (mx - mn);
    float rs = 0.f;
    #pragma unroll
    for (int v = 0; v < 64; ++v) {
        row[v] = (row[v] - mn) * inv;
        rs += row[v];
    }
    float d = rsqrtf(rs);
    __shared__ float sd[64];
    sd[i] = d;
    __syncthreads();
    #pragma unroll
    for (int v = 0; v < 64; ++v) adjn[i*64 + v] = row[v] * d * sd[v];
}

// ---------------------------------------------------------------------------
// Kernel 3b: att + M. grid = N*V (1024) blocks (one per (b,j)), block = 256.
// att[i][t] = softmax_t(leakyrelu(Ei[b,i,t]+Ej[b,j,t])); M[b,j,t,v] stored
// as M[((b*16+t)*64+j)*64+v].
// ---------------------------------------------------------------------------
__global__ __launch_bounds__(256) void att_m_k(const float* __restrict__ Ei,
                                               const float* __restrict__ Ej,
                                               const float* __restrict__ adjn,
                                               float* __restrict__ M) {
    int b = blockIdx.x >> 6;
    int j = blockIdx.x & 63;
    int tid = threadIdx.x;
    __shared__ float s_att[64][16];

    if (tid < 64) {
        int i = tid;
        const float* eip = Ei + ((size_t)b*V_ + i)*T_;
        const float* ejp = Ej + ((size_t)b*V_ + j)*T_;
        float ev[16];
        float mx = -1e30f;
        #pragma unroll
        for (int t = 0; t < 16; ++t) {
            float x = eip[t] + ejp[t];
            x = (x >= 0.f) ? x : ALPHA_ * x;
            ev[t] = x;
            mx = fmaxf(mx, x);
        }
        float s = 0.f;
        #pragma unroll
        for (int t = 0; t < 16; ++t) {
            ev[t] = __expf(ev[t] - mx);
            s += ev[t];
        }
        float invs = 1.f / s;
        #pragma unroll
        for (int t = 0; t < 16; ++t) s_att[i][t] = ev[t] * invs;
    }
    __syncthreads();

    int v = tid & 63, tq = tid >> 6;  // 4 t per thread
    float acc[4] = {0.f, 0.f, 0.f, 0.f};
    for (int i = 0; i < 64; ++i) {
        float an = adjn[i*64 + v];
        #pragma unroll
        for (int u = 0; u < 4; ++u) acc[u] += s_att[i][tq*4 + u] * an;
    }
    float* Mp = M + ((size_t)b*T_*V_ + j)*V_ + v;
    #pragma unroll
    for (int u = 0; u < 4; ++u)
        Mp[(size_t)(tq*4 + u) * (V_*V_)] = acc[u];
}

// ---------------------------------------------------------------------------
// Kernel 4: out[b,p,t,v] = elu( sum_j A[p,j]*M[j,v] ),  A[p,j]=Wh[b,t,p,j].
// grid = N*T*8 (2048): 128-p chunk per block. block = 256:
// 32 p-quads (tid&31) x 8 v-groups of 8 (tid>>5).
// ---------------------------------------------------------------------------
__global__ __launch_bounds__(256) void out_k(const float* __restrict__ Wh,
                                             const float* __restrict__ M,
                                             float* __restrict__ out) {
    int bi = blockIdx.x;
    int pc = bi & 7;
    int t  = (bi >> 3) & 15;
    int b  = bi >> 7;

    __shared__ float sM[64*64];     // [j][v]
    __shared__ float sA[128*65];    // [p][j], padded leading dim

    int tid = threadIdx.x;
    const float* Mb = M + (size_t)(b*T_ + t) * (V_*V_);
    for (int i = tid; i < 4096; i += 256) sM[i] = Mb[i];
    const float* Ab = Wh + (((size_t)b*T_ + t)*P_ + pc*128) * V_;
    for (int i = tid; i < 8192; i += 256) sA[(i >> 6)*65 + (i & 63)] = Ab[i];
    __syncthreads();

    int pg = tid & 31;
    int vg = tid >> 5;
    const float* sArow = sA + pg*4*65;

    float acc[4][8];
    #pragma unroll
    for (int u = 0; u < 4; ++u)
        #pragma unroll
        for (int vv = 0; vv < 8; ++vv) acc[u][vv] = 0.f;

    #pragma unroll 4
    for (int jj = 0; jj < 64; ++jj) {
        float a0 = sArow[jj];
        float a1 = sArow[65 + jj];
        float a2 = sArow[130 + jj];
        float a3 = sArow[195 + jj];
        #pragma unroll
        for (int vv = 0; vv < 8; ++vv) {
            float m = sM[jj*64 + vg*8 + vv];
            acc[0][vv] += a0 * m;
            acc[1][vv] += a1 * m;
            acc[2][vv] += a2 * m;
            acc[3][vv] += a3 * m;
        }
    }

    #pragma unroll
    for (int u = 0; u < 4; ++u) {
        int p = pc*128 + pg*4 + u;
        float* op = out + (((size_t)b*P_ + p)*T_ + t)*V_ + vg*8;
        #pragma unroll
        for (int vv = 0; vv < 8; ++vv) {
            float x = acc[u][vv];
            op[vv] = (x > 0.f) ? x : (__expf(x) - 1.f);
        }
    }
}

// ---------------------------------------------------------------------------
extern "C" void kernel_launch(void* const* d_in, const int* in_sizes, int n_in,
                              void* d_out, int out_size, void* d_ws, size_t ws_size,
                              hipStream_t stream) {
    const float* X  = (const float*)d_in[0];  // h: (16,32,32,16,64)
    const float* CW = (const float*)d_in[1];  // conv_w: (3,3,16,16)
    const float* CB = (const float*)d_in[2];  // conv_b: (16,)
    const float* av = (const float*)d_in[3];  // a: (2048,1)
    const float* Bm = (const float*)d_in[4];  // B: (64,64)
    float* outp = (float*)d_out;

    float* ws   = (float*)d_ws;
    float* Wh   = ws;                          // 16,777,216 floats (b,t,p,v)
    float* M    = Wh + (size_t)N_*T_*P_*V_;    // 1,048,576
    float* Ei   = M  + (size_t)N_*T_*V_*V_;    // 16,384
    float* Ej   = Ei + (size_t)N_*V_*T_;       // 16,384
    float* adjn = Ej + (size_t)N_*V_*T_;       // 4,096

    conv_k <<<N_*H_,      256, 0, stream>>>(X, CW, CB, Wh);
    eiej_k <<<N_*T_,      256, 0, stream>>>(Wh, av, Ei, Ej);
    adjn_k <<<1,           64, 0, stream>>>(Bm, adjn);
    att_m_k<<<N_*V_,      256, 0, stream>>>(Ei, Ej, adjn, M);
    out_k  <<<N_*T_*8,    256, 0, stream>>>(Wh, M, outp);
}

// Round 2
// 161.825 us; speedup vs baseline: 1.2529x; 1.2529x over previous
//
#include <hip/hip_runtime.h>
#include <math.h>

#define ALPHA_ 0.2f
#define N_ 16
#define H_ 32
#define W_ 32
#define T_ 16
#define V_ 64
#define P_ (H_*W_)  // 1024

// ---------------------------------------------------------------------------
// Kernel 1: conv. grid = N*H*4 (2048) with XCD-chunked swizzle.
// block = 256 = 64 v-lanes x 4 w-groups; each thread computes 2 w-positions,
// all 16 t. Weights read via wave-uniform indices -> s_load (no LDS).
// Wh stored as (b, t, p, v), p = h*32+w.
// ---------------------------------------------------------------------------
__global__ __launch_bounds__(256) void conv_k(const float* __restrict__ X,
                                              const float* __restrict__ CW,
                                              const float* __restrict__ CB,
                                              float* __restrict__ Wh) {
    // 2048 blocks = 8 XCDs x 256: give each XCD a contiguous (b,hh) range.
    int orig = blockIdx.x;
    int bi   = (orig & 7) * 256 + (orig >> 3);
    int ws   = bi & 3;
    int hh   = (bi >> 2) & 31;
    int b    = bi >> 7;

    int tid = threadIdx.x;
    int v   = tid & 63;
    int wg  = tid >> 6;        // 0..3 (wave-uniform)
    int w0  = ws * 8 + wg * 2; // first of 2 output w-positions

    float acc[2][16];
    #pragma unroll
    for (int t = 0; t < 16; ++t) {
        float cb = CB[t];      // uniform -> s_load
        acc[0][t] = cb;
        acc[1][t] = cb;
    }

    const float* Xb = X + (size_t)b * (H_*W_*T_*V_) + v;
    const bool m0 = (w0 - 1) >= 0;   // wave-uniform edge masks
    const bool m3 = (w0 + 2) < W_;

    for (int dh = 0; dh < 3; ++dh) {
        int hy = hh + dh - 1;
        if ((unsigned)hy >= (unsigned)H_) continue;
        const float* Xr = Xb + ((size_t)hy * W_ + (w0 - 1)) * (size_t)(T_*V_);
        const float* wd = CW + dh * 3 * 256;  // [dw][ti][t], dw stride 256

        #pragma unroll 4
        for (int ti = 0; ti < 16; ++ti) {
            const float* xp = Xr + (size_t)ti * V_;
            float x0 = m0 ? xp[0]    : 0.f;   // wx = w0-1
            float x1 =      xp[1024];         // wx = w0
            float x2 =      xp[2048];         // wx = w0+1
            float x3 = m3 ? xp[3072] : 0.f;   // wx = w0+2
            const float* wr = wd + ti * 16;
            #pragma unroll
            for (int t = 0; t < 16; ++t) {
                float wa = wr[t];         // dw=0 (uniform -> SGPR)
                float wb = wr[256 + t];   // dw=1
                float wc = wr[512 + t];   // dw=2
                acc[0][t] += x0 * wa + x1 * wb + x2 * wc;
                acc[1][t] += x1 * wa + x2 * wb + x3 * wc;
            }
        }
    }

    int p = hh * W_ + w0;
    float* Wp = Wh + ((size_t)b * T_ * P_ + p) * V_ + v;
    #pragma unroll
    for (int t = 0; t < 16; ++t) {
        Wp[(size_t)t * (P_*V_)]       = acc[0][t];
        Wp[(size_t)t * (P_*V_) + V_]  = acc[1][t];
    }
}

// ---------------------------------------------------------------------------
// Kernel 2: Ei/Ej. grid = N*T (256) blocks of 256.
// Ei[b,v,q] = sum_{e,w,t} Wh[b,t,(2q+e)*32+w,v] * a[e*1024+w*16+t]
// Ej same with +512 offset into a. Stored (b, v, q) contiguous in q.
// ---------------------------------------------------------------------------
__global__ __launch_bounds__(256) void eiej_k(const float* __restrict__ Wh,
                                              const float* __restrict__ av,
                                              float* __restrict__ Ei,
                                              float* __restrict__ Ej) {
    int b = blockIdx.x >> 4;
    int q = blockIdx.x & 15;
    int tid = threadIdx.x, v = tid & 63, g = tid >> 6;  // g: 4 t-groups

    float si = 0.f, sj = 0.f;
    for (int e = 0; e < 2; ++e) {
        int hh = 2*q + e;
        #pragma unroll
        for (int tt = 0; tt < 4; ++tt) {
            int t = g*4 + tt;
            const float* base = Wh + (((size_t)b*T_ + t)*P_ + hh*W_) * V_ + v;
            #pragma unroll 8
            for (int w = 0; w < 32; ++w) {
                float x  = base[(size_t)w * V_];
                float ai = av[e*1024 + w*16 + t];
                float aj = av[e*1024 + w*16 + t + 512];
                si += x * ai;
                sj += x * aj;
            }
        }
    }
    __shared__ float ri[4][64], rj[4][64];
    ri[g][v] = si; rj[g][v] = sj;
    __syncthreads();
    if (g == 0) {
        float a0 = ri[0][v] + ri[1][v] + ri[2][v] + ri[3][v];
        float a1 = rj[0][v] + rj[1][v] + rj[2][v] + rj[3][v];
        Ei[((size_t)b*V_ + v)*T_ + q] = a0;
        Ej[((size_t)b*V_ + v)*T_ + q] = a1;
    }
}

// ---------------------------------------------------------------------------
// Kernel 3a: adj_norm from B. 1 block, 64 threads (one wave), lane = row.
// ---------------------------------------------------------------------------
__global__ __launch_bounds__(64) void adjn_k(const float* __restrict__ Bm,
                                             float* __restrict__ adjn) {
    int i = threadIdx.x;  // row 0..63
    float row[64];
    float mn = 1e30f, mx = -1e30f;
    #pragma unroll
    for (int v = 0; v < 64; ++v) {
        float x = Bm[i*64 + v] + (v == i ? 1.f : 0.f);
        row[v] = x;
        mn = fminf(mn, x);
        mx = fmaxf(mx, x);
    }
    #pragma unroll
    for (int off = 32; off > 0; off >>= 1) {
        mn = fminf(mn, __shfl_xor(mn, off));
        mx = fmaxf(mx, __shfl_xor(mx, off));
    }
    float inv = 1.f / (mx - mn);
    float rs = 0.f;
    #pragma unroll
    for (int v = 0; v < 64; ++v) {
        row[v] = (row[v] - mn) * inv;
        rs += row[v];
    }
    float d = rsqrtf(rs);
    __shared__ float sd[64];
    sd[i] = d;
    __syncthreads();
    #pragma unroll
    for (int v = 0; v < 64; ++v) adjn[i*64 + v] = row[v] * d * sd[v];
}

// ---------------------------------------------------------------------------
// Kernel 3b: att + M. grid = N*V (1024) blocks (one per (b,j)), block = 256.
// att[i][t] = softmax_t(leakyrelu(Ei[b,i,t]+Ej[b,j,t])); M[b,j,t,v] stored
// as M[((b*16+t)*64+j)*64+v].
// ---------------------------------------------------------------------------
__global__ __launch_bounds__(256) void att_m_k(const float* __restrict__ Ei,
                                               const float* __restrict__ Ej,
                                               const float* __restrict__ adjn,
                                               float* __restrict__ M) {
    int b = blockIdx.x >> 6;
    int j = blockIdx.x & 63;
    int tid = threadIdx.x;
    __shared__ float s_att[64][16];

    if (tid < 64) {
        int i = tid;
        const float* eip = Ei + ((size_t)b*V_ + i)*T_;
        const float* ejp = Ej + ((size_t)b*V_ + j)*T_;
        float ev[16];
        float mx = -1e30f;
        #pragma unroll
        for (int t = 0; t < 16; ++t) {
            float x = eip[t] + ejp[t];
            x = (x >= 0.f) ? x : ALPHA_ * x;
            ev[t] = x;
            mx = fmaxf(mx, x);
        }
        float s = 0.f;
        #pragma unroll
        for (int t = 0; t < 16; ++t) {
            ev[t] = __expf(ev[t] - mx);
            s += ev[t];
        }
        float invs = 1.f / s;
        #pragma unroll
        for (int t = 0; t < 16; ++t) s_att[i][t] = ev[t] * invs;
    }
    __syncthreads();

    int v = tid & 63, tq = tid >> 6;  // 4 t per thread
    float acc[4] = {0.f, 0.f, 0.f, 0.f};
    for (int i = 0; i < 64; ++i) {
        float an = adjn[i*64 + v];
        #pragma unroll
        for (int u = 0; u < 4; ++u) acc[u] += s_att[i][tq*4 + u] * an;
    }
    float* Mp = M + ((size_t)b*T_*V_ + j)*V_ + v;
    #pragma unroll
    for (int u = 0; u < 4; ++u)
        Mp[(size_t)(tq*4 + u) * (V_*V_)] = acc[u];
}

// ---------------------------------------------------------------------------
// Kernel 4: out[b,p,t,v] = elu( sum_j A[p,j]*M[j,v] ),  A[p,j]=Wh[b,t,p,j].
// grid = N*T*8 (2048): 128-p chunk per block. block = 256:
// 32 p-quads (tid&31) x 8 v-groups of 8 (tid>>5).
// ---------------------------------------------------------------------------
__global__ __launch_bounds__(256) void out_k(const float* __restrict__ Wh,
                                             const float* __restrict__ M,
                                             float* __restrict__ out) {
    int bi = blockIdx.x;
    int pc = bi & 7;
    int t  = (bi >> 3) & 15;
    int b  = bi >> 7;

    __shared__ float sM[64*64];     // [j][v]
    __shared__ float sA[128*65];    // [p][j], padded leading dim

    int tid = threadIdx.x;
    const float* Mb = M + (size_t)(b*T_ + t) * (V_*V_);
    for (int i = tid; i < 4096; i += 256) sM[i] = Mb[i];
    const float* Ab = Wh + (((size_t)b*T_ + t)*P_ + pc*128) * V_;
    for (int i = tid; i < 8192; i += 256) sA[(i >> 6)*65 + (i & 63)] = Ab[i];
    __syncthreads();

    int pg = tid & 31;
    int vg = tid >> 5;
    const float* sArow = sA + pg*4*65;

    float acc[4][8];
    #pragma unroll
    for (int u = 0; u < 4; ++u)
        #pragma unroll
        for (int vv = 0; vv < 8; ++vv) acc[u][vv] = 0.f;

    #pragma unroll 4
    for (int jj = 0; jj < 64; ++jj) {
        float a0 = sArow[jj];
        float a1 = sArow[65 + jj];
        float a2 = sArow[130 + jj];
        float a3 = sArow[195 + jj];
        #pragma unroll
        for (int vv = 0; vv < 8; ++vv) {
            float m = sM[jj*64 + vg*8 + vv];
            acc[0][vv] += a0 * m;
            acc[1][vv] += a1 * m;
            acc[2][vv] += a2 * m;
            acc[3][vv] += a3 * m;
        }
    }

    #pragma unroll
    for (int u = 0; u < 4; ++u) {
        int p = pc*128 + pg*4 + u;
        float* op = out + (((size_t)b*P_ + p)*T_ + t)*V_ + vg*8;
        #pragma unroll
        for (int vv = 0; vv < 8; ++vv) {
            float x = acc[u][vv];
            op[vv] = (x > 0.f) ? x : (__expf(x) - 1.f);
        }
    }
}

// ---------------------------------------------------------------------------
extern "C" void kernel_launch(void* const* d_in, const int* in_sizes, int n_in,
                              void* d_out, int out_size, void* d_ws, size_t ws_size,
                              hipStream_t stream) {
    const float* X  = (const float*)d_in[0];  // h: (16,32,32,16,64)
    const float* CW = (const float*)d_in[1];  // conv_w: (3,3,16,16)
    const float* CB = (const float*)d_in[2];  // conv_b: (16,)
    const float* av = (const float*)d_in[3];  // a: (2048,1)
    const float* Bm = (const float*)d_in[4];  // B: (64,64)
    float* outp = (float*)d_out;

    float* ws   = (float*)d_ws;
    float* Wh   = ws;                          // 16,777,216 floats (b,t,p,v)
    float* M    = Wh + (size_t)N_*T_*P_*V_;    // 1,048,576
    float* Ei   = M  + (size_t)N_*T_*V_*V_;    // 16,384
    float* Ej   = Ei + (size_t)N_*V_*T_;       // 16,384
    float* adjn = Ej + (size_t)N_*V_*T_;       // 4,096

    conv_k <<<N_*H_*4,    256, 0, stream>>>(X, CW, CB, Wh);
    eiej_k <<<N_*T_,      256, 0, stream>>>(Wh, av, Ei, Ej);
    adjn_k <<<1,           64, 0, stream>>>(Bm, adjn);
    att_m_k<<<N_*V_,      256, 0, stream>>>(Ei, Ej, adjn, M);
    out_k  <<<N_*T_*8,    256, 0, stream>>>(Wh, M, outp);
}

// Round 3
// 139.483 us; speedup vs baseline: 1.4536x; 1.1602x over previous
//
#include <hip/hip_runtime.h>
#include <hip/hip_bf16.h>
#include <math.h>

#define ALPHA_ 0.2f
#define N_ 16
#define H_ 32
#define W_ 32
#define T_ 16
#define V_ 64
#define P_ (H_*W_)  // 1024

typedef __bf16 bf16x8 __attribute__((ext_vector_type(8)));
typedef float  f32x4  __attribute__((ext_vector_type(4)));

// ---------------------------------------------------------------------------
// Kernel 1: conv (fp32 compute, bf16 store). grid = 2048 (XCD-swizzled):
// (b, hh, ws half-row, th t-half). block 256 = 64 v-lanes x 4 wg.
// Thread: 4 w-positions x 8 t. Weights in LDS, read as float4 (b128 bcast).
// Whb stored bf16 as (b, t, p, v), p = h*32+w.
// ---------------------------------------------------------------------------
__global__ __launch_bounds__(256) void conv_k(const float* __restrict__ X,
                                              const float* __restrict__ CW,
                                              const float* __restrict__ CB,
                                              __hip_bfloat16* __restrict__ Whb) {
    __shared__ __align__(16) float s_cw[2304];  // [dh][dw][ti][t]
    int tid = threadIdx.x;
    for (int i = tid; i < 2304; i += 256) s_cw[i] = CW[i];
    __syncthreads();

    int orig = blockIdx.x;
    int bi   = (orig & 7) * 256 + (orig >> 3);  // 8 XCDs x 256 contiguous
    int th   = bi & 1;          // t-half: t = th*8 + tt
    int ws   = (bi >> 1) & 1;   // w-half
    int hh   = (bi >> 2) & 31;
    int b    = bi >> 7;

    int v  = tid & 63;
    int wg = tid >> 6;          // 0..3, wave-uniform
    int w0 = ws*16 + wg*4;      // 4 output w-positions

    float acc[4][8];
    #pragma unroll
    for (int tt = 0; tt < 8; ++tt) {
        float cb = CB[th*8 + tt];
        #pragma unroll
        for (int u = 0; u < 4; ++u) acc[u][tt] = cb;
    }

    const bool mL = (w0 > 0);        // wave-uniform edge masks
    const bool mR = (w0 + 4 < W_);
    const float* Xb = X + (size_t)b * (H_*W_*T_*V_) + v;

    for (int dh = 0; dh < 3; ++dh) {
        int hy = hh + dh - 1;
        if ((unsigned)hy >= (unsigned)H_) continue;
        const float* xp = Xb + ((size_t)hy*W_ + (w0 - 1)) * (size_t)(T_*V_);
        const float* wbase = s_cw + dh*768 + th*8;

        #pragma unroll 1
        for (int ti = 0; ti < 16; ++ti) {
            float x[6];
            x[0] = mL ? xp[0] : 0.f;
            x[1] = xp[1024];
            x[2] = xp[2048];
            x[3] = xp[3072];
            x[4] = xp[4096];
            x[5] = mR ? xp[5120] : 0.f;
            #pragma unroll
            for (int g = 0; g < 2; ++g) {
                f32x4 wa = *(const f32x4*)(wbase + (0*16 + ti)*16 + g*4);
                f32x4 wb = *(const f32x4*)(wbase + (1*16 + ti)*16 + g*4);
                f32x4 wc = *(const f32x4*)(wbase + (2*16 + ti)*16 + g*4);
                #pragma unroll
                for (int e = 0; e < 4; ++e) {
                    int t = g*4 + e;
                    float fa = wa[e], fb = wb[e], fc = wc[e];
                    #pragma unroll
                    for (int u = 0; u < 4; ++u)
                        acc[u][t] += x[u]*fa + x[u+1]*fb + x[u+2]*fc;
                }
            }
            xp += 64;  // next ti
        }
    }

    #pragma unroll
    for (int tt = 0; tt < 8; ++tt) {
        __hip_bfloat16* Wp = Whb
            + ((size_t)(b*T_ + th*8 + tt)*P_ + hh*W_ + w0)*V_ + v;
        #pragma unroll
        for (int u = 0; u < 4; ++u)
            Wp[(size_t)u*V_] = __float2bfloat16(acc[u][tt]);
    }
}

// ---------------------------------------------------------------------------
// Kernel 2: Ei/Ej from bf16 Whb. grid = N*T (256) blocks of 256.
// Ei[b,v,q] = sum_{e,w,t} Whb[b,t,(2q+e)*32+w,v] * a[e*1024+w*16+t]
// ---------------------------------------------------------------------------
__global__ __launch_bounds__(256) void eiej_k(const __hip_bfloat16* __restrict__ Whb,
                                              const float* __restrict__ av,
                                              float* __restrict__ Ei,
                                              float* __restrict__ Ej) {
    int b = blockIdx.x >> 4;
    int q = blockIdx.x & 15;
    int tid = threadIdx.x, v = tid & 63, g = tid >> 6;

    float si = 0.f, sj = 0.f;
    for (int e = 0; e < 2; ++e) {
        int hh = 2*q + e;
        #pragma unroll
        for (int tt = 0; tt < 4; ++tt) {
            int t = g*4 + tt;
            const __hip_bfloat16* base =
                Whb + (((size_t)b*T_ + t)*P_ + hh*W_) * V_ + v;
            #pragma unroll 8
            for (int w = 0; w < 32; ++w) {
                float x  = __bfloat162float(base[(size_t)w * V_]);
                float ai = av[e*1024 + w*16 + t];
                float aj = av[e*1024 + w*16 + t + 512];
                si += x * ai;
                sj += x * aj;
            }
        }
    }
    __shared__ float ri[4][64], rj[4][64];
    ri[g][v] = si; rj[g][v] = sj;
    __syncthreads();
    if (g == 0) {
        float a0 = ri[0][v] + ri[1][v] + ri[2][v] + ri[3][v];
        float a1 = rj[0][v] + rj[1][v] + rj[2][v] + rj[3][v];
        Ei[((size_t)b*V_ + v)*T_ + q] = a0;
        Ej[((size_t)b*V_ + v)*T_ + q] = a1;
    }
}

// ---------------------------------------------------------------------------
// Kernel 3a: adj_norm from B. 1 block, 64 threads.
// ---------------------------------------------------------------------------
__global__ __launch_bounds__(64) void adjn_k(const float* __restrict__ Bm,
                                             float* __restrict__ adjn) {
    int i = threadIdx.x;
    float row[64];
    float mn = 1e30f, mx = -1e30f;
    #pragma unroll
    for (int v = 0; v < 64; ++v) {
        float x = Bm[i*64 + v] + (v == i ? 1.f : 0.f);
        row[v] = x;
        mn = fminf(mn, x);
        mx = fmaxf(mx, x);
    }
    #pragma unroll
    for (int off = 32; off > 0; off >>= 1) {
        mn = fminf(mn, __shfl_xor(mn, off));
        mx = fmaxf(mx, __shfl_xor(mx, off));
    }
    float inv = 1.f / (mx - mn);
    float rs = 0.f;
    #pragma unroll
    for (int v = 0; v < 64; ++v) {
        row[v] = (row[v] - mn) * inv;
        rs += row[v];
    }
    float d = rsqrtf(rs);
    __shared__ float sd[64];
    sd[i] = d;
    __syncthreads();
    #pragma unroll
    for (int v = 0; v < 64; ++v) adjn[i*64 + v] = row[v] * d * sd[v];
}

// ---------------------------------------------------------------------------
// Kernel 3b: att + Mt. grid = N*V (1024), one (b,j) per block, block 256.
// Mt[b][t][v][j] bf16 (B-operand layout for out_k MFMA).
// ---------------------------------------------------------------------------
__global__ __launch_bounds__(256) void att_m_k(const float* __restrict__ Ei,
                                               const float* __restrict__ Ej,
                                               const float* __restrict__ adjn,
                                               __hip_bfloat16* __restrict__ Mt) {
    int b = blockIdx.x >> 6;
    int j = blockIdx.x & 63;
    int tid = threadIdx.x;
    __shared__ float s_att[64][16];

    if (tid < 64) {
        int i = tid;
        const float* eip = Ei + ((size_t)b*V_ + i)*T_;
        const float* ejp = Ej + ((size_t)b*V_ + j)*T_;
        float ev[16];
        float mx = -1e30f;
        #pragma unroll
        for (int t = 0; t < 16; ++t) {
            float x = eip[t] + ejp[t];
            x = (x >= 0.f) ? x : ALPHA_ * x;
            ev[t] = x;
            mx = fmaxf(mx, x);
        }
        float s = 0.f;
        #pragma unroll
        for (int t = 0; t < 16; ++t) {
            ev[t] = __expf(ev[t] - mx);
            s += ev[t];
        }
        float invs = 1.f / s;
        #pragma unroll
        for (int t = 0; t < 16; ++t) s_att[i][t] = ev[t] * invs;
    }
    __syncthreads();

    int v = tid & 63, tq = tid >> 6;  // 4 t per thread
    float acc[4] = {0.f, 0.f, 0.f, 0.f};
    for (int i = 0; i < 64; ++i) {
        float an = adjn[i*64 + v];
        #pragma unroll
        for (int u = 0; u < 4; ++u) acc[u] += s_att[i][tq*4 + u] * an;
    }
    #pragma unroll
    for (int u = 0; u < 4; ++u) {
        int t = tq*4 + u;
        Mt[(((size_t)b*T_ + t)*V_ + v)*V_ + j] = __float2bfloat16(acc[u]);
    }
}

// ---------------------------------------------------------------------------
// Kernel 4 (MFMA): out[b,p,t,v] = elu( sum_j Whb[b,t,p,j] * Mt[b,t,v,j] ).
// Per (b,t): GEMM 1024(p) x 64(j=K) x 64(v). grid = N*T*8 (2048): 128 p/block.
// block 256 = 4 waves; wave: 2 p-tiles x 4 v-tiles, K = 2 frags of 32.
// A-frag: m = lane&15 (p), k = (lane>>4)*8+i (j).  B-frag: n = lane&15 (v),
// same k-map (k-permutation cancels since A/B share it).
// C/D: col = lane&15 (v), row = (lane>>4)*4+r (p)  [guide-verified].
// ---------------------------------------------------------------------------
__global__ __launch_bounds__(256) void out_k(const __hip_bfloat16* __restrict__ Whb,
                                             const __hip_bfloat16* __restrict__ Mt,
                                             float* __restrict__ out) {
    int bi = blockIdx.x;
    int pc = bi & 7;
    int t  = (bi >> 3) & 15;
    int b  = bi >> 7;

    int tid  = threadIdx.x;
    int lane = tid & 63;
    int wid  = tid >> 6;
    int lm   = lane & 15;
    int lk   = lane >> 4;

    const __hip_bfloat16* Ab = Whb + ((size_t)(b*T_ + t)*P_ + pc*128) * V_;
    const __hip_bfloat16* Bb = Mt  + (size_t)(b*T_ + t) * (V_*V_);

    f32x4 acc[2][4];
    #pragma unroll
    for (int pt = 0; pt < 2; ++pt)
        #pragma unroll
        for (int vt = 0; vt < 4; ++vt) acc[pt][vt] = (f32x4){0.f,0.f,0.f,0.f};

    #pragma unroll
    for (int kf = 0; kf < 2; ++kf) {
        int ko = kf*32 + lk*8;
        bf16x8 a0 = *(const bf16x8*)(Ab + ((size_t)((wid*2+0)*16 + lm))*V_ + ko);
        bf16x8 a1 = *(const bf16x8*)(Ab + ((size_t)((wid*2+1)*16 + lm))*V_ + ko);
        #pragma unroll
        for (int vt = 0; vt < 4; ++vt) {
            bf16x8 bf = *(const bf16x8*)(Bb + ((size_t)(vt*16 + lm))*V_ + ko);
            acc[0][vt] = __builtin_amdgcn_mfma_f32_16x16x32_bf16(a0, bf, acc[0][vt], 0, 0, 0);
            acc[1][vt] = __builtin_amdgcn_mfma_f32_16x16x32_bf16(a1, bf, acc[1][vt], 0, 0, 0);
        }
    }

    #pragma unroll
    for (int pt = 0; pt < 2; ++pt) {
        #pragma unroll
        for (int vt = 0; vt < 4; ++vt) {
            #pragma unroll
            for (int r = 0; r < 4; ++r) {
                int p  = pc*128 + (wid*2 + pt)*16 + lk*4 + r;
                int vv = vt*16 + lm;
                float x = acc[pt][vt][r];
                x = (x > 0.f) ? x : (__expf(x) - 1.f);
                out[((size_t)(b*P_ + p)*T_ + t)*V_ + vv] = x;
            }
        }
    }
}

// ---------------------------------------------------------------------------
extern "C" void kernel_launch(void* const* d_in, const int* in_sizes, int n_in,
                              void* d_out, int out_size, void* d_ws, size_t ws_size,
                              hipStream_t stream) {
    const float* X  = (const float*)d_in[0];  // h: (16,32,32,16,64)
    const float* CW = (const float*)d_in[1];  // conv_w: (3,3,16,16)
    const float* CB = (const float*)d_in[2];  // conv_b: (16,)
    const float* av = (const float*)d_in[3];  // a: (2048,1)
    const float* Bm = (const float*)d_in[4];  // B: (64,64)
    float* outp = (float*)d_out;

    __hip_bfloat16* Whb = (__hip_bfloat16*)d_ws;            // 16*16*1024*64 bf16
    __hip_bfloat16* Mt  = Whb + (size_t)N_*T_*P_*V_;        // 16*16*64*64 bf16
    float* Ei   = (float*)(Mt + (size_t)N_*T_*V_*V_);       // 16*64*16
    float* Ej   = Ei + (size_t)N_*V_*T_;
    float* adjn = Ej + (size_t)N_*V_*T_;

    conv_k <<<2048,   256, 0, stream>>>(X, CW, CB, Whb);
    eiej_k <<<N_*T_,  256, 0, stream>>>(Whb, av, Ei, Ej);
    adjn_k <<<1,       64, 0, stream>>>(Bm, adjn);
    att_m_k<<<N_*V_,  256, 0, stream>>>(Ei, Ej, adjn, Mt);
    out_k  <<<N_*T_*8, 256, 0, stream>>>(Whb, Mt, outp);
}

// Round 4
// 95.824 us; speedup vs baseline: 2.1158x; 1.4556x over previous
//
#include <hip/hip_runtime.h>
#include <hip/hip_bf16.h>
#include <math.h>

#define ALPHA_ 0.2f
#define N_ 16
#define H_ 32
#define W_ 32
#define T_ 16
#define V_ 64
#define P_ (H_*W_)  // 1024

typedef __bf16 bf16x8 __attribute__((ext_vector_type(8)));
typedef float  f32x4  __attribute__((ext_vector_type(4)));

static __device__ inline bf16x8 zero8() {
    bf16x8 z;
    #pragma unroll
    for (int i = 0; i < 8; ++i) z[i] = (__bf16)0.f;
    return z;
}

static __device__ inline unsigned short bf16bits(float f) {
    __hip_bfloat16 b = __float2bfloat16(f);
    return *reinterpret_cast<unsigned short*>(&b);
}

// ---------------------------------------------------------------------------
// Kernel 0: transpose X[b,h,w,ti,v] f32 -> Xt[b][h+1][w][v][ti] bf16.
// h-halo rows (hp==0, hp==33) are zero-filled. grid = 16*34 = 544 blocks.
// ---------------------------------------------------------------------------
__global__ __launch_bounds__(256) void tr_k(const float* __restrict__ X,
                                            __hip_bfloat16* __restrict__ Xt) {
    int b  = blockIdx.x / 34;
    int hp = blockIdx.x % 34;
    int tid = threadIdx.x;
    __hip_bfloat16* dstRow = Xt + ((size_t)b*34 + hp) * (size_t)(W_*V_*T_);

    if (hp == 0 || hp == 33) {            // zero halo row: 32*64*16 bf16 = 64KB
        uint4 z = {0u,0u,0u,0u};
        uint4* d = (uint4*)dstRow;
        for (int i = tid; i < (W_*V_*T_*2)/16; i += 256) d[i] = z;
        return;
    }
    int h = hp - 1;
    __shared__ float sl[4][64][17];
    const float* Xr = X + ((size_t)b*H_ + h) * (size_t)(W_*T_*V_);
    int ti = tid >> 4, v4 = (tid & 15) * 4;   // read mapping
    int vv = tid >> 2, tq = tid & 3;          // write mapping

    for (int wb = 0; wb < 8; ++wb) {
        #pragma unroll
        for (int w = 0; w < 4; ++w) {
            f32x4 x = *(const f32x4*)(Xr + (size_t)(wb*4 + w)*(T_*V_) + tid*4);
            sl[w][v4+0][ti] = x[0];
            sl[w][v4+1][ti] = x[1];
            sl[w][v4+2][ti] = x[2];
            sl[w][v4+3][ti] = x[3];
        }
        __syncthreads();
        #pragma unroll
        for (int w = 0; w < 4; ++w) {
            unsigned short u0 = bf16bits(sl[w][vv][tq*4+0]);
            unsigned short u1 = bf16bits(sl[w][vv][tq*4+1]);
            unsigned short u2 = bf16bits(sl[w][vv][tq*4+2]);
            unsigned short u3 = bf16bits(sl[w][vv][tq*4+3]);
            uint2 pk;
            pk.x = (unsigned)u0 | ((unsigned)u1 << 16);
            pk.y = (unsigned)u2 | ((unsigned)u3 << 16);
            *(uint2*)(dstRow + ((size_t)(wb*4 + w)*V_ + vv)*T_ + tq*4) = pk;
        }
        __syncthreads();
    }
}

// ---------------------------------------------------------------------------
// Kernel 0b: prep — B-fragment table for conv MFMA + adj_norm. 1 block, 64 thr.
// Bfrag[dw][pr][lane][i] with the SAME (lane,i)->k convention as conv's A:
//   k = (lane>>4)*8 + i;  pr0: dh = kg>>1, ti = (kg&1)*8+i;
//   pr1: kg<2 -> dh=2 (same ti formula), kg>=2 -> 0 (annihilates garbage A).
// ---------------------------------------------------------------------------
__global__ __launch_bounds__(64) void prep_k(const float* __restrict__ CW,
                                             const float* __restrict__ Bm,
                                             __hip_bfloat16* __restrict__ Bfrag,
                                             float* __restrict__ adjn) {
    int lane = threadIdx.x;
    int t = lane & 15, kg = lane >> 4;
    #pragma unroll
    for (int dw = 0; dw < 3; ++dw) {
        #pragma unroll
        for (int pr = 0; pr < 2; ++pr) {
            __hip_bfloat16* dst = Bfrag + ((size_t)((dw*2+pr)*64 + lane))*8;
            #pragma unroll
            for (int i = 0; i < 8; ++i) {
                int ti = (kg & 1)*8 + i;
                float val;
                if (pr == 0) { int dh = kg >> 1; val = CW[((dh*3+dw)*16+ti)*16 + t]; }
                else          val = (kg < 2) ? CW[((2*3+dw)*16+ti)*16 + t] : 0.f;
                dst[i] = __float2bfloat16(val);
            }
        }
    }
    // adj_norm
    int i = lane;
    float row[64];
    float mn = 1e30f, mx = -1e30f;
    #pragma unroll
    for (int v = 0; v < 64; ++v) {
        float x = Bm[i*64 + v] + (v == i ? 1.f : 0.f);
        row[v] = x;
        mn = fminf(mn, x);
        mx = fmaxf(mx, x);
    }
    #pragma unroll
    for (int off = 32; off > 0; off >>= 1) {
        mn = fminf(mn, __shfl_xor(mn, off));
        mx = fmaxf(mx, __shfl_xor(mx, off));
    }
    float inv = 1.f / (mx - mn);
    float rs = 0.f;
    #pragma unroll
    for (int v = 0; v < 64; ++v) {
        row[v] = (row[v] - mn) * inv;
        rs += row[v];
    }
    float d = rsqrtf(rs);
    __shared__ float sd[64];
    sd[i] = d;
    __syncthreads();
    #pragma unroll
    for (int v = 0; v < 64; ++v) adjn[i*64 + v] = row[v] * d * sd[v];
}

// ---------------------------------------------------------------------------
// Kernel 1: conv via MFMA. grid = 2048 (XCD-grouped: 2 b per XCD):
// bi -> (b, h, vg). block 256 = 4 waves, wave = 8-w chunk.
// Wave computes D[16v x 16t] per w: A = Xt rows (m=v, k=(dh,ti)), B = Bfrag.
// Whb stored bf16 as (b, t, p, v).
// ---------------------------------------------------------------------------
__global__ __launch_bounds__(256) void conv_k(const __hip_bfloat16* __restrict__ Xt,
                                              const __hip_bfloat16* __restrict__ Bfrag,
                                              const float* __restrict__ CB,
                                              __hip_bfloat16* __restrict__ Whb) {
    int orig = blockIdx.x;
    int bi   = (orig & 7) * 256 + (orig >> 3);
    int b    = bi >> 7;
    int rem  = bi & 127;
    int h    = rem >> 2;
    int vg   = rem & 3, vb = vg * 16;

    int tid = threadIdx.x, lane = tid & 63, wc = tid >> 6;
    int lm = lane & 15, kg = lane >> 4;

    bf16x8 Bf01[3], Bf2[3];
    #pragma unroll
    for (int dw = 0; dw < 3; ++dw) {
        Bf01[dw] = *(const bf16x8*)(Bfrag + (size_t)((dw*2+0)*64 + lane)*8);
        Bf2 [dw] = *(const bf16x8*)(Bfrag + (size_t)((dw*2+1)*64 + lane)*8);
    }
    float cb = CB[lm];
    f32x4 acc[8];
    #pragma unroll
    for (int wi = 0; wi < 8; ++wi) acc[wi] = (f32x4){cb, cb, cb, cb};

    const __hip_bfloat16* base01 =
        Xt + ((size_t)((b*34 + h + (kg>>1))*W_)*V_ + vb + lm)*T_ + (kg&1)*8;
    const __hip_bfloat16* base2  =
        Xt + ((size_t)((b*34 + h + 2)*W_)*V_ + vb + lm)*T_ + (kg&1)*8;

    #pragma unroll
    for (int u = 0; u < 10; ++u) {
        int wxu = wc*8 + u - 1;                  // input w (unpadded)
        bf16x8 f01 = zero8(), f2 = zero8();
        if ((unsigned)wxu < (unsigned)W_) {      // wave-uniform edge test
            f01 = *(const bf16x8*)(base01 + (size_t)wxu*(V_*T_));
            f2  = *(const bf16x8*)(base2  + (size_t)wxu*(V_*T_));
        }
        #pragma unroll
        for (int dw = 0; dw < 3; ++dw) {
            int wi = u - dw;                     // compile-time
            if (wi >= 0 && wi < 8) {
                acc[wi] = __builtin_amdgcn_mfma_f32_16x16x32_bf16(f01, Bf01[dw], acc[wi], 0, 0, 0);
                acc[wi] = __builtin_amdgcn_mfma_f32_16x16x32_bf16(f2,  Bf2 [dw], acc[wi], 0, 0, 0);
            }
        }
    }

    // D: col = lm = t, rows v = vb + kg*4 + r
    #pragma unroll
    for (int wi = 0; wi < 8; ++wi) {
        int p = h*W_ + wc*8 + wi;
        unsigned short u0 = bf16bits(acc[wi][0]);
        unsigned short u1 = bf16bits(acc[wi][1]);
        unsigned short u2 = bf16bits(acc[wi][2]);
        unsigned short u3 = bf16bits(acc[wi][3]);
        uint2 pk;
        pk.x = (unsigned)u0 | ((unsigned)u1 << 16);
        pk.y = (unsigned)u2 | ((unsigned)u3 << 16);
        *(uint2*)(Whb + ((size_t)(b*T_ + lm)*P_ + p)*V_ + vb + kg*4) = pk;
    }
}

// ---------------------------------------------------------------------------
// Kernel 2: Ei/Ej from bf16 Whb. grid = N*T (256) blocks of 256.
// ---------------------------------------------------------------------------
__global__ __launch_bounds__(256) void eiej_k(const __hip_bfloat16* __restrict__ Whb,
                                              const float* __restrict__ av,
                                              float* __restrict__ Ei,
                                              float* __restrict__ Ej) {
    int b = blockIdx.x >> 4;
    int q = blockIdx.x & 15;
    int tid = threadIdx.x, v = tid & 63, g = tid >> 6;

    float si = 0.f, sj = 0.f;
    for (int e = 0; e < 2; ++e) {
        int hh = 2*q + e;
        #pragma unroll
        for (int tt = 0; tt < 4; ++tt) {
            int t = g*4 + tt;
            const __hip_bfloat16* base =
                Whb + (((size_t)b*T_ + t)*P_ + hh*W_) * V_ + v;
            #pragma unroll 8
            for (int w = 0; w < 32; ++w) {
                float x  = __bfloat162float(base[(size_t)w * V_]);
                float ai = av[e*1024 + w*16 + t];
                float aj = av[e*1024 + w*16 + t + 512];
                si += x * ai;
                sj += x * aj;
            }
        }
    }
    __shared__ float ri[4][64], rj[4][64];
    ri[g][v] = si; rj[g][v] = sj;
    __syncthreads();
    if (g == 0) {
        float a0 = ri[0][v] + ri[1][v] + ri[2][v] + ri[3][v];
        float a1 = rj[0][v] + rj[1][v] + rj[2][v] + rj[3][v];
        Ei[((size_t)b*V_ + v)*T_ + q] = a0;
        Ej[((size_t)b*V_ + v)*T_ + q] = a1;
    }
}

// ---------------------------------------------------------------------------
// Kernel 3: att + Mt. grid = N*V (1024), one (b,j) per block, block 256.
// Mt[b][t][v][j] bf16 (B-operand layout for out_k MFMA).
// ---------------------------------------------------------------------------
__global__ __launch_bounds__(256) void att_m_k(const float* __restrict__ Ei,
                                               const float* __restrict__ Ej,
                                               const float* __restrict__ adjn,
                                               __hip_bfloat16* __restrict__ Mt) {
    int b = blockIdx.x >> 6;
    int j = blockIdx.x & 63;
    int tid = threadIdx.x;
    __shared__ float s_att[64][16];

    if (tid < 64) {
        int i = tid;
        const float* eip = Ei + ((size_t)b*V_ + i)*T_;
        const float* ejp = Ej + ((size_t)b*V_ + j)*T_;
        float ev[16];
        float mx = -1e30f;
        #pragma unroll
        for (int t = 0; t < 16; ++t) {
            float x = eip[t] + ejp[t];
            x = (x >= 0.f) ? x : ALPHA_ * x;
            ev[t] = x;
            mx = fmaxf(mx, x);
        }
        float s = 0.f;
        #pragma unroll
        for (int t = 0; t < 16; ++t) {
            ev[t] = __expf(ev[t] - mx);
            s += ev[t];
        }
        float invs = 1.f / s;
        #pragma unroll
        for (int t = 0; t < 16; ++t) s_att[i][t] = ev[t] * invs;
    }
    __syncthreads();

    int v = tid & 63, tq = tid >> 6;
    float acc[4] = {0.f, 0.f, 0.f, 0.f};
    for (int i = 0; i < 64; ++i) {
        float an = adjn[i*64 + v];
        #pragma unroll
        for (int u = 0; u < 4; ++u) acc[u] += s_att[i][tq*4 + u] * an;
    }
    #pragma unroll
    for (int u = 0; u < 4; ++u) {
        int t = tq*4 + u;
        Mt[(((size_t)b*T_ + t)*V_ + v)*V_ + j] = __float2bfloat16(acc[u]);
    }
}

// ---------------------------------------------------------------------------
// Kernel 4 (MFMA): out[b,p,t,v] = elu( sum_j Whb[b,t,p,j] * Mt[b,t,v,j] ).
// ---------------------------------------------------------------------------
__global__ __launch_bounds__(256) void out_k(const __hip_bfloat16* __restrict__ Whb,
                                             const __hip_bfloat16* __restrict__ Mt,
                                             float* __restrict__ out) {
    int bi = blockIdx.x;
    int pc = bi & 7;
    int t  = (bi >> 3) & 15;
    int b  = bi >> 7;

    int tid  = threadIdx.x;
    int lane = tid & 63;
    int wid  = tid >> 6;
    int lm   = lane & 15;
    int lk   = lane >> 4;

    const __hip_bfloat16* Ab = Whb + ((size_t)(b*T_ + t)*P_ + pc*128) * V_;
    const __hip_bfloat16* Bb = Mt  + (size_t)(b*T_ + t) * (V_*V_);

    f32x4 acc[2][4];
    #pragma unroll
    for (int pt = 0; pt < 2; ++pt)
        #pragma unroll
        for (int vt = 0; vt < 4; ++vt) acc[pt][vt] = (f32x4){0.f,0.f,0.f,0.f};

    #pragma unroll
    for (int kf = 0; kf < 2; ++kf) {
        int ko = kf*32 + lk*8;
        bf16x8 a0 = *(const bf16x8*)(Ab + ((size_t)((wid*2+0)*16 + lm))*V_ + ko);
        bf16x8 a1 = *(const bf16x8*)(Ab + ((size_t)((wid*2+1)*16 + lm))*V_ + ko);
        #pragma unroll
        for (int vt = 0; vt < 4; ++vt) {
            bf16x8 bf = *(const bf16x8*)(Bb + ((size_t)(vt*16 + lm))*V_ + ko);
            acc[0][vt] = __builtin_amdgcn_mfma_f32_16x16x32_bf16(a0, bf, acc[0][vt], 0, 0, 0);
            acc[1][vt] = __builtin_amdgcn_mfma_f32_16x16x32_bf16(a1, bf, acc[1][vt], 0, 0, 0);
        }
    }

    #pragma unroll
    for (int pt = 0; pt < 2; ++pt) {
        #pragma unroll
        for (int vt = 0; vt < 4; ++vt) {
            #pragma unroll
            for (int r = 0; r < 4; ++r) {
                int p  = pc*128 + (wid*2 + pt)*16 + lk*4 + r;
                int vv = vt*16 + lm;
                float x = acc[pt][vt][r];
                x = (x > 0.f) ? x : (__expf(x) - 1.f);
                out[((size_t)(b*P_ + p)*T_ + t)*V_ + vv] = x;
            }
        }
    }
}

// ---------------------------------------------------------------------------
extern "C" void kernel_launch(void* const* d_in, const int* in_sizes, int n_in,
                              void* d_out, int out_size, void* d_ws, size_t ws_size,
                              hipStream_t stream) {
    const float* X  = (const float*)d_in[0];  // h: (16,32,32,16,64)
    const float* CW = (const float*)d_in[1];  // conv_w: (3,3,16,16)
    const float* CB = (const float*)d_in[2];  // conv_b: (16,)
    const float* av = (const float*)d_in[3];  // a: (2048,1)
    const float* Bm = (const float*)d_in[4];  // B: (64,64)
    float* outp = (float*)d_out;

    // ws: Whb (33.55MB) | Mt (2MB) | Ei | Ej | adjn | Bfrag   (~36MB total)
    __hip_bfloat16* Whb = (__hip_bfloat16*)d_ws;
    __hip_bfloat16* Mt  = Whb + (size_t)N_*T_*P_*V_;
    float* Ei   = (float*)(Mt + (size_t)N_*T_*V_*V_);
    float* Ej   = Ei + (size_t)N_*V_*T_;
    float* adjn = Ej + (size_t)N_*V_*T_;
    __hip_bfloat16* Bfrag = (__hip_bfloat16*)(adjn + V_*V_);

    // Xt scratch (35.65MB) lives in d_out; out_k overwrites it at the end.
    __hip_bfloat16* Xt = (__hip_bfloat16*)d_out;

    tr_k   <<<N_*34,   256, 0, stream>>>(X, Xt);
    prep_k <<<1,        64, 0, stream>>>(CW, Bm, Bfrag, adjn);
    conv_k <<<2048,    256, 0, stream>>>(Xt, Bfrag, CB, Whb);
    eiej_k <<<N_*T_,   256, 0, stream>>>(Whb, av, Ei, Ej);
    att_m_k<<<N_*V_,   256, 0, stream>>>(Ei, Ej, adjn, Mt);
    out_k  <<<N_*T_*8, 256, 0, stream>>>(Whb, Mt, outp);
}

// Round 5
// 77.994 us; speedup vs baseline: 2.5995x; 1.2286x over previous
//
#include <hip/hip_runtime.h>
#include <hip/hip_bf16.h>
#include <math.h>

#define ALPHA_ 0.2f
#define N_ 16
#define H_ 32
#define W_ 32
#define T_ 16
#define V_ 64
#define P_ (H_*W_)  // 1024

typedef __bf16 bf16x8 __attribute__((ext_vector_type(8)));
typedef float  f32x4  __attribute__((ext_vector_type(4)));

static __device__ inline bf16x8 zero8() {
    bf16x8 z;
    #pragma unroll
    for (int i = 0; i < 8; ++i) z[i] = (__bf16)0.f;
    return z;
}

static __device__ inline unsigned short bf16bits(float f) {
    __hip_bfloat16 b = __float2bfloat16(f);
    return *reinterpret_cast<unsigned short*>(&b);
}

// ---------------------------------------------------------------------------
// Kernel 0: transpose X[b,h,w,ti,v] f32 -> Xt[b][h+1][w][v][ti] bf16, with
// zero h-halo rows. Block 544 (the extra one) instead builds the conv MFMA
// B-fragment table and adj_norm. grid = 16*34 + 1 = 545 blocks.
// ---------------------------------------------------------------------------
__global__ __launch_bounds__(256) void tr_prep_k(const float* __restrict__ X,
                                                 __hip_bfloat16* __restrict__ Xt,
                                                 const float* __restrict__ CW,
                                                 const float* __restrict__ Bm,
                                                 __hip_bfloat16* __restrict__ Bfrag,
                                                 float* __restrict__ adjn) {
    int bid = blockIdx.x;
    int tid = threadIdx.x;

    if (bid == N_*34) {
        // ---- prep: Bfrag[dw][pr][lane][i] + adj_norm. Threads 0..63 only,
        // with a convergent __syncthreads in the middle.
        __shared__ float sd[64];
        float row[64];
        int lane = tid;
        if (tid < 64) {
            int t = lane & 15, kg = lane >> 4;
            #pragma unroll
            for (int dw = 0; dw < 3; ++dw) {
                #pragma unroll
                for (int pr = 0; pr < 2; ++pr) {
                    __hip_bfloat16* dst = Bfrag + ((size_t)((dw*2+pr)*64 + lane))*8;
                    #pragma unroll
                    for (int i = 0; i < 8; ++i) {
                        int ti = (kg & 1)*8 + i;
                        float val;
                        if (pr == 0) { int dh = kg >> 1; val = CW[((dh*3+dw)*16+ti)*16 + t]; }
                        else          val = (kg < 2) ? CW[((2*3+dw)*16+ti)*16 + t] : 0.f;
                        dst[i] = __float2bfloat16(val);
                    }
                }
            }
            int i = lane;
            float mn = 1e30f, mx = -1e30f;
            #pragma unroll
            for (int v = 0; v < 64; ++v) {
                float x = Bm[i*64 + v] + (v == i ? 1.f : 0.f);
                row[v] = x;
                mn = fminf(mn, x);
                mx = fmaxf(mx, x);
            }
            #pragma unroll
            for (int off = 32; off > 0; off >>= 1) {
                mn = fminf(mn, __shfl_xor(mn, off));
                mx = fmaxf(mx, __shfl_xor(mx, off));
            }
            float inv = 1.f / (mx - mn);
            float rs = 0.f;
            #pragma unroll
            for (int v = 0; v < 64; ++v) {
                row[v] = (row[v] - mn) * inv;
                rs += row[v];
            }
            sd[i] = rsqrtf(rs);
        }
        __syncthreads();
        if (tid < 64) {
            float d = sd[tid];
            #pragma unroll
            for (int v = 0; v < 64; ++v) adjn[tid*64 + v] = row[v] * d * sd[v];
        }
        return;
    }

    int b  = bid / 34;
    int hp = bid % 34;
    __hip_bfloat16* dstRow = Xt + ((size_t)b*34 + hp) * (size_t)(W_*V_*T_);

    if (hp == 0 || hp == 33) {            // zero halo row
        uint4 z = {0u,0u,0u,0u};
        uint4* d = (uint4*)dstRow;
        for (int i = tid; i < (W_*V_*T_*2)/16; i += 256) d[i] = z;
        return;
    }
    int h = hp - 1;
    __shared__ float sl[4][64][17];
    const float* Xr = X + ((size_t)b*H_ + h) * (size_t)(W_*T_*V_);
    int ti = tid >> 4, v4 = (tid & 15) * 4;   // read mapping
    int vv = tid >> 2, tq = tid & 3;          // write mapping

    for (int wb = 0; wb < 8; ++wb) {
        #pragma unroll
        for (int w = 0; w < 4; ++w) {
            f32x4 x = *(const f32x4*)(Xr + (size_t)(wb*4 + w)*(T_*V_) + tid*4);
            sl[w][v4+0][ti] = x[0];
            sl[w][v4+1][ti] = x[1];
            sl[w][v4+2][ti] = x[2];
            sl[w][v4+3][ti] = x[3];
        }
        __syncthreads();
        #pragma unroll
        for (int w = 0; w < 4; ++w) {
            unsigned short u0 = bf16bits(sl[w][vv][tq*4+0]);
            unsigned short u1 = bf16bits(sl[w][vv][tq*4+1]);
            unsigned short u2 = bf16bits(sl[w][vv][tq*4+2]);
            unsigned short u3 = bf16bits(sl[w][vv][tq*4+3]);
            uint2 pk;
            pk.x = (unsigned)u0 | ((unsigned)u1 << 16);
            pk.y = (unsigned)u2 | ((unsigned)u3 << 16);
            *(uint2*)(dstRow + ((size_t)(wb*4 + w)*V_ + vv)*T_ + tq*4) = pk;
        }
        __syncthreads();
    }
}

// ---------------------------------------------------------------------------
// Kernel 1: conv via MFMA + fused Ei/Ej partial reduction.
// grid = 2048 (XCD-grouped), bi -> (b, h, vg). block 256 = 4 waves (w-chunks).
// Whb stored bf16 as (b, t, p, v). Eih*[b][h][v]: per-h partials of Ei/Ej
// computed from the fp32 accumulators:
//   Eihi[b,h,v] = sum_{w,t} acc(b,h,w,t,v) * av[(h&1)*1024 + w*16 + t]
//   Eihj: same with +512.
// ---------------------------------------------------------------------------
__global__ __launch_bounds__(256) void conv_k(const __hip_bfloat16* __restrict__ Xt,
                                              const __hip_bfloat16* __restrict__ Bfrag,
                                              const float* __restrict__ CB,
                                              const float* __restrict__ av,
                                              __hip_bfloat16* __restrict__ Whb,
                                              float* __restrict__ Eihi,
                                              float* __restrict__ Eihj) {
    int orig = blockIdx.x;
    int bi   = (orig & 7) * 256 + (orig >> 3);
    int b    = bi >> 7;
    int rem  = bi & 127;
    int h    = rem >> 2;
    int vg   = rem & 3, vb = vg * 16;

    int tid = threadIdx.x, lane = tid & 63, wc = tid >> 6;
    int lm = lane & 15, kg = lane >> 4;

    bf16x8 Bf01[3], Bf2[3];
    #pragma unroll
    for (int dw = 0; dw < 3; ++dw) {
        Bf01[dw] = *(const bf16x8*)(Bfrag + (size_t)((dw*2+0)*64 + lane)*8);
        Bf2 [dw] = *(const bf16x8*)(Bfrag + (size_t)((dw*2+1)*64 + lane)*8);
    }
    float cb = CB[lm];
    f32x4 acc[8];
    #pragma unroll
    for (int wi = 0; wi < 8; ++wi) acc[wi] = (f32x4){cb, cb, cb, cb};

    const __hip_bfloat16* base01 =
        Xt + ((size_t)((b*34 + h + (kg>>1))*W_)*V_ + vb + lm)*T_ + (kg&1)*8;
    const __hip_bfloat16* base2  =
        Xt + ((size_t)((b*34 + h + 2)*W_)*V_ + vb + lm)*T_ + (kg&1)*8;

    #pragma unroll
    for (int u = 0; u < 10; ++u) {
        int wxu = wc*8 + u - 1;                  // input w (unpadded)
        bf16x8 f01 = zero8(), f2 = zero8();
        if ((unsigned)wxu < (unsigned)W_) {      // wave-uniform edge test
            f01 = *(const bf16x8*)(base01 + (size_t)wxu*(V_*T_));
            f2  = *(const bf16x8*)(base2  + (size_t)wxu*(V_*T_));
        }
        #pragma unroll
        for (int dw = 0; dw < 3; ++dw) {
            int wi = u - dw;                     // compile-time
            if (wi >= 0 && wi < 8) {
                acc[wi] = __builtin_amdgcn_mfma_f32_16x16x32_bf16(f01, Bf01[dw], acc[wi], 0, 0, 0);
                acc[wi] = __builtin_amdgcn_mfma_f32_16x16x32_bf16(f2,  Bf2 [dw], acc[wi], 0, 0, 0);
            }
        }
    }

    // ---- fused Ei/Ej partials (fp32 acc; lane holds t=lm, v=vb+kg*4+r) ----
    float si[4] = {0.f,0.f,0.f,0.f}, sj[4] = {0.f,0.f,0.f,0.f};
    {
        const float* avb = av + (h & 1)*1024 + wc*8*16 + lm;
        #pragma unroll
        for (int wi = 0; wi < 8; ++wi) {
            float ai = avb[wi*16];
            float aj = avb[wi*16 + 512];
            #pragma unroll
            for (int r = 0; r < 4; ++r) {
                si[r] += acc[wi][r] * ai;
                sj[r] += acc[wi][r] * aj;
            }
        }
        #pragma unroll
        for (int off = 1; off < 16; off <<= 1) {
            #pragma unroll
            for (int r = 0; r < 4; ++r) {
                si[r] += __shfl_xor(si[r], off);
                sj[r] += __shfl_xor(sj[r], off);
            }
        }
    }
    __shared__ float sEi[4][16], sEj[4][16];
    if (lm == 0) {
        #pragma unroll
        for (int r = 0; r < 4; ++r) {
            sEi[wc][kg*4 + r] = si[r];
            sEj[wc][kg*4 + r] = sj[r];
        }
    }

    // ---- Whb store: col = lm = t, rows v = vb + kg*4 + r ----
    #pragma unroll
    for (int wi = 0; wi < 8; ++wi) {
        int p = h*W_ + wc*8 + wi;
        unsigned short u0 = bf16bits(acc[wi][0]);
        unsigned short u1 = bf16bits(acc[wi][1]);
        unsigned short u2 = bf16bits(acc[wi][2]);
        unsigned short u3 = bf16bits(acc[wi][3]);
        uint2 pk;
        pk.x = (unsigned)u0 | ((unsigned)u1 << 16);
        pk.y = (unsigned)u2 | ((unsigned)u3 << 16);
        *(uint2*)(Whb + ((size_t)(b*T_ + lm)*P_ + p)*V_ + vb + kg*4) = pk;
    }

    __syncthreads();
    if (tid < 16) {
        float a = sEi[0][tid] + sEi[1][tid] + sEi[2][tid] + sEi[3][tid];
        float c = sEj[0][tid] + sEj[1][tid] + sEj[2][tid] + sEj[3][tid];
        Eihi[((size_t)b*H_ + h)*V_ + vb + tid] = a;
        Eihj[((size_t)b*H_ + h)*V_ + vb + tid] = c;
    }
}

// ---------------------------------------------------------------------------
// Kernel 2: att + Mt. grid = N*V (1024), one (b,j) per block, block 256.
// Ei[b,i,t] = Eihi[b][2t][i] + Eihi[b][2t+1][i]; Ej analogous with j.
// Mt[b][t][v][j] bf16 (B-operand layout for out_k MFMA).
// ---------------------------------------------------------------------------
__global__ __launch_bounds__(256) void att_m_k(const float* __restrict__ Eihi,
                                               const float* __restrict__ Eihj,
                                               const float* __restrict__ adjn,
                                               __hip_bfloat16* __restrict__ Mt) {
    int b = blockIdx.x >> 6;
    int j = blockIdx.x & 63;
    int tid = threadIdx.x;
    __shared__ float s_att[64][16];

    if (tid < 64) {
        int i = tid;
        const float* ebi = Eihi + (size_t)b*H_*V_;
        const float* ebj = Eihj + (size_t)b*H_*V_;
        float ev[16];
        float mx = -1e30f;
        #pragma unroll
        for (int t = 0; t < 16; ++t) {
            float x = ebi[(2*t)*V_ + i] + ebi[(2*t+1)*V_ + i]
                    + ebj[(2*t)*V_ + j] + ebj[(2*t+1)*V_ + j];
            x = (x >= 0.f) ? x : ALPHA_ * x;
            ev[t] = x;
            mx = fmaxf(mx, x);
        }
        float s = 0.f;
        #pragma unroll
        for (int t = 0; t < 16; ++t) {
            ev[t] = __expf(ev[t] - mx);
            s += ev[t];
        }
        float invs = 1.f / s;
        #pragma unroll
        for (int t = 0; t < 16; ++t) s_att[i][t] = ev[t] * invs;
    }
    __syncthreads();

    int v = tid & 63, tq = tid >> 6;
    float acc[4] = {0.f, 0.f, 0.f, 0.f};
    for (int i = 0; i < 64; ++i) {
        float an = adjn[i*64 + v];
        #pragma unroll
        for (int u = 0; u < 4; ++u) acc[u] += s_att[i][tq*4 + u] * an;
    }
    #pragma unroll
    for (int u = 0; u < 4; ++u) {
        int t = tq*4 + u;
        Mt[(((size_t)b*T_ + t)*V_ + v)*V_ + j] = __float2bfloat16(acc[u]);
    }
}

// ---------------------------------------------------------------------------
// Kernel 3 (MFMA): out[b,p,t,v] = elu( sum_j Whb[b,t,p,j] * Mt[b,t,v,j] ).
// ---------------------------------------------------------------------------
__global__ __launch_bounds__(256) void out_k(const __hip_bfloat16* __restrict__ Whb,
                                             const __hip_bfloat16* __restrict__ Mt,
                                             float* __restrict__ out) {
    int bi = blockIdx.x;
    int pc = bi & 7;
    int t  = (bi >> 3) & 15;
    int b  = bi >> 7;

    int tid  = threadIdx.x;
    int lane = tid & 63;
    int wid  = tid >> 6;
    int lm   = lane & 15;
    int lk   = lane >> 4;

    const __hip_bfloat16* Ab = Whb + ((size_t)(b*T_ + t)*P_ + pc*128) * V_;
    const __hip_bfloat16* Bb = Mt  + (size_t)(b*T_ + t) * (V_*V_);

    f32x4 acc[2][4];
    #pragma unroll
    for (int pt = 0; pt < 2; ++pt)
        #pragma unroll
        for (int vt = 0; vt < 4; ++vt) acc[pt][vt] = (f32x4){0.f,0.f,0.f,0.f};

    #pragma unroll
    for (int kf = 0; kf < 2; ++kf) {
        int ko = kf*32 + lk*8;
        bf16x8 a0 = *(const bf16x8*)(Ab + ((size_t)((wid*2+0)*16 + lm))*V_ + ko);
        bf16x8 a1 = *(const bf16x8*)(Ab + ((size_t)((wid*2+1)*16 + lm))*V_ + ko);
        #pragma unroll
        for (int vt = 0; vt < 4; ++vt) {
            bf16x8 bf = *(const bf16x8*)(Bb + ((size_t)(vt*16 + lm))*V_ + ko);
            acc[0][vt] = __builtin_amdgcn_mfma_f32_16x16x32_bf16(a0, bf, acc[0][vt], 0, 0, 0);
            acc[1][vt] = __builtin_amdgcn_mfma_f32_16x16x32_bf16(a1, bf, acc[1][vt], 0, 0, 0);
        }
    }

    #pragma unroll
    for (int pt = 0; pt < 2; ++pt) {
        #pragma unroll
        for (int vt = 0; vt < 4; ++vt) {
            #pragma unroll
            for (int r = 0; r < 4; ++r) {
                int p  = pc*128 + (wid*2 + pt)*16 + lk*4 + r;
                int vv = vt*16 + lm;
                float x = acc[pt][vt][r];
                x = (x > 0.f) ? x : (__expf(x) - 1.f);
                out[((size_t)(b*P_ + p)*T_ + t)*V_ + vv] = x;
            }
        }
    }
}

// ---------------------------------------------------------------------------
extern "C" void kernel_launch(void* const* d_in, const int* in_sizes, int n_in,
                              void* d_out, int out_size, void* d_ws, size_t ws_size,
                              hipStream_t stream) {
    const float* X  = (const float*)d_in[0];  // h: (16,32,32,16,64)
    const float* CW = (const float*)d_in[1];  // conv_w: (3,3,16,16)
    const float* CB = (const float*)d_in[2];  // conv_b: (16,)
    const float* av = (const float*)d_in[3];  // a: (2048,1)
    const float* Bm = (const float*)d_in[4];  // B: (64,64)
    float* outp = (float*)d_out;

    // ws: Whb (33.55MB) | Mt (2MB) | Eihi | Eihj | adjn | Bfrag
    __hip_bfloat16* Whb = (__hip_bfloat16*)d_ws;
    __hip_bfloat16* Mt  = Whb + (size_t)N_*T_*P_*V_;
    float* Eihi = (float*)(Mt + (size_t)N_*T_*V_*V_);   // 16*32*64
    float* Eihj = Eihi + (size_t)N_*H_*V_;
    float* adjn = Eihj + (size_t)N_*H_*V_;
    __hip_bfloat16* Bfrag = (__hip_bfloat16*)(adjn + V_*V_);

    // Xt scratch (35.65MB) lives in d_out; out_k overwrites it at the end.
    __hip_bfloat16* Xt = (__hip_bfloat16*)d_out;

    tr_prep_k<<<N_*34 + 1, 256, 0, stream>>>(X, Xt, CW, Bm, Bfrag, adjn);
    conv_k   <<<2048,      256, 0, stream>>>(Xt, Bfrag, CB, av, Whb, Eihi, Eihj);
    att_m_k  <<<N_*V_,     256, 0, stream>>>(Eihi, Eihj, adjn, Mt);
    out_k    <<<N_*T_*8,   256, 0, stream>>>(Whb, Mt, outp);
}